// Round 10
// baseline (415.941 us; speedup 1.0000x reference)
//
#include <hip/hip_runtime.h>
#include <hip/hip_bf16.h>
#include <math.h>

#define NODES 20000
#define EDGES 320000
#define NB 3
#define TOTN (NODES * NB)   // 60000
#define TOTE (EDGES * NB)   // 960000
#define D_IN 128
#define D_H 304
#define SCAN_B 59           // ceil(60000/1024)
#define SLICES 40
#define SLICE_E (EDGES / SLICES)   // 8000

typedef __attribute__((ext_vector_type(4))) float f32x4;
typedef __attribute__((ext_vector_type(2))) float f32x2;

__device__ __forceinline__ unsigned short f2bf(float f) {
    unsigned u = __float_as_uint(f);
    unsigned r = (u + 0x7fffu + ((u >> 16) & 1u)) >> 16;   // RNE
    return (unsigned short)r;
}
// async global->LDS, 16 B per lane; LDS dst must be wave-uniform base + lane*16
__device__ __forceinline__ void gload16(const void* g, void* l) {
    __builtin_amdgcn_global_load_lds(
        (const __attribute__((address_space(1))) unsigned*)g,
        (__attribute__((address_space(3))) unsigned*)l, 16, 0, 0);
}

// ------- pack x1|x2|x3 fp32 -> X fp8 (60000 x 128), pre-scaled by inv_out -------
__global__ void k_pack8(const float4* __restrict__ x1, const float4* __restrict__ x2,
                        const float4* __restrict__ x3, const float* __restrict__ inv_out,
                        unsigned* __restrict__ q) {
    const int per = NODES * D_IN / 4;  // out dwords per graph (32 per row)
    int i = blockIdx.x * 256 + threadIdx.x;
    if (i >= 3 * per) return;
    const float4* s; int j;
    if (i < per)          { s = x1; j = i; }
    else if (i < 2 * per) { s = x2; j = i - per; }
    else                  { s = x3; j = i - 2 * per; }
    float4 v = s[j];
    float sc = inv_out[i >> 5];   // 32 dwords per row, global node id
    int p = __builtin_amdgcn_cvt_pk_fp8_f32(v.x * sc, v.y * sc, 0, false);
    p = __builtin_amdgcn_cvt_pk_fp8_f32(v.z * sc, v.w * sc, p, true);
    q[i] = (unsigned)p;
}

// ------- per-(graph,slice) LDS histograms: no global atomics -------
__global__ __launch_bounds__(256, 1) void k_hist(
    const int* __restrict__ s1, const int* __restrict__ d1,
    const int* __restrict__ s2, const int* __restrict__ d2,
    const int* __restrict__ s3, const int* __restrict__ d3,
    int* __restrict__ partial_in, int* __restrict__ partial_out) {
    __shared__ int hist[NODES];   // 80 KB
    int g = blockIdx.x / SLICES, s = blockIdx.x % SLICES;
    bool isOut = (blockIdx.y == 1);
    const int* ep;
    if (isOut) ep = (g == 0) ? s1 : ((g == 1) ? s2 : s3);
    else       ep = (g == 0) ? d1 : ((g == 1) ? d2 : d3);
    ep += s * SLICE_E;
    for (int i = threadIdx.x; i < NODES; i += 256) hist[i] = 0;
    __syncthreads();
    const int4* ep4 = (const int4*)ep;
    for (int i = threadIdx.x; i < SLICE_E / 4; i += 256) {
        int4 v = ep4[i];
        atomicAdd(&hist[v.x], 1);
        atomicAdd(&hist[v.y], 1);
        atomicAdd(&hist[v.z], 1);
        atomicAdd(&hist[v.w], 1);
    }
    __syncthreads();
    int* po = (isOut ? partial_out : partial_in) + (size_t)blockIdx.x * NODES;
    for (int i = threadIdx.x; i < NODES; i += 256) po[i] = hist[i];
}

// ------- degrees from partials + inv factors + block-level scan (fused) -------
__global__ void k_degscan(const int* __restrict__ partial_in,
                          const int* __restrict__ partial_out,
                          float* __restrict__ inv_in, float* __restrict__ inv_out,
                          int* __restrict__ excl, int* __restrict__ btot) {
    __shared__ int wsum[16];
    int b = blockIdx.x, t = threadIdx.x;
    int i = b * 1024 + t;
    int lane = t & 63, wid = t >> 6;
    int v = 0;
    if (i < TOTN) {
        int g = i / NODES, ln = i - g * NODES;
        const int* pi = partial_in + (size_t)g * SLICES * NODES + ln;
        const int* po = partial_out + (size_t)g * SLICES * NODES + ln;
        int ci = 0, co = 0;
        #pragma unroll
        for (int s = 0; s < SLICES; s++) { ci += pi[s * NODES]; co += po[s * NODES]; }
        v = ci;
        inv_in[i]  = 1.0f / sqrtf((float)max(ci, 1));
        inv_out[i] = 1.0f / sqrtf((float)max(co, 1));
    }
    int sv = v;
    #pragma unroll
    for (int o = 1; o < 64; o <<= 1) {
        int u = __shfl_up(sv, o, 64);
        if (lane >= o) sv += u;
    }
    if (lane == 63) wsum[wid] = sv;
    __syncthreads();
    if (t < 16) {
        int w = wsum[t];
        #pragma unroll
        for (int o = 1; o < 16; o <<= 1) {
            int u = __shfl_up(w, o, 16);
            if (t >= o) w += u;
        }
        wsum[t] = w;
    }
    __syncthreads();
    int wbase = (wid > 0) ? wsum[wid - 1] : 0;
    if (i < TOTN) excl[i] = wbase + sv - v;
    if (t == 0) btot[b] = wsum[15];
}

// ------- scan of block totals + zero pooled + zero csr slack (fused) -------
__global__ void k_scanB(const int* __restrict__ btot, int* __restrict__ boff,
                        int* __restrict__ csr_slack, int* __restrict__ pooled) {
    int t = threadIdx.x;  // 64
    if (t < 16) csr_slack[t] = 0;   // zero csr[TOTE..TOTE+15] over-read slack
    #pragma unroll
    for (int i = t; i < 320; i += 64) pooled[i] = 0;
    int v = (t < SCAN_B) ? btot[t] : 0;
    int sv = v;
    #pragma unroll
    for (int o = 1; o < 64; o <<= 1) {
        int u = __shfl_up(sv, o, 64);
        if (t >= o) sv += u;
    }
    if (t < SCAN_B) boff[t] = sv - v;  // exclusive
}

// ------- row_ptr apply + per-(slice,node) CSR base offsets (fused) -------
__global__ void k_offC(const int* __restrict__ excl, const int* __restrict__ boff,
                       const int* __restrict__ partial_in,
                       int* __restrict__ row_ptr, int* __restrict__ O) {
    int n = blockIdx.x * 256 + threadIdx.x;
    if (n >= TOTN) {
        if (n == TOTN) row_ptr[TOTN] = TOTE;
        return;
    }
    if (n == 0) row_ptr[TOTN] = TOTE;
    int rp = excl[n] + boff[n >> 10];
    row_ptr[n] = rp;
    int g = n / NODES, ln = n - g * NODES;
    const int* pi = partial_in + (size_t)g * SLICES * NODES + ln;
    int* on = O + (size_t)g * SLICES * NODES + ln;
    int run = rp;
    #pragma unroll
    for (int s = 0; s < SLICES; s++) {
        on[s * NODES] = run;
        run += pi[s * NODES];
    }
}

// ------- CSR fill via LDS cursors (global-atomic-free) -------
__global__ __launch_bounds__(256, 1) void k_fill2(
    const int* __restrict__ s1, const int* __restrict__ d1,
    const int* __restrict__ s2, const int* __restrict__ d2,
    const int* __restrict__ s3, const int* __restrict__ d3,
    const int* __restrict__ O, int* __restrict__ csr) {
    __shared__ int cur[NODES];   // 80 KB
    int g = blockIdx.x / SLICES, s = blockIdx.x % SLICES;
    const int* sp = (g == 0) ? s1 : ((g == 1) ? s2 : s3);
    const int* dp = (g == 0) ? d1 : ((g == 1) ? d2 : d3);
    sp += s * SLICE_E; dp += s * SLICE_E;
    const int* on = O + (size_t)blockIdx.x * NODES;
    for (int i = threadIdx.x; i < NODES; i += 256) cur[i] = on[i];
    __syncthreads();
    int base = g * NODES;
    const int4* sp4 = (const int4*)sp;
    const int4* dp4 = (const int4*)dp;
    for (int i = threadIdx.x; i < SLICE_E / 4; i += 256) {
        int4 dv = dp4[i];
        int4 sv = sp4[i];
        int p0 = atomicAdd(&cur[dv.x], 1); csr[p0] = sv.x + base;
        int p1 = atomicAdd(&cur[dv.y], 1); csr[p1] = sv.y + base;
        int p2 = atomicAdd(&cur[dv.z], 1); csr[p2] = sv.z + base;
        int p3 = atomicAdd(&cur[dv.w], 1); csr[p3] = sv.w + base;
    }
}

// ------- SpMM layer 1: 4 edges/gather (16 lanes x uint2) -> fp8 out ----------
// X8 rows: 128 fp8 = 16 uint2. One node per wave. P8 rows 128 B.
__global__ void k_spmm_l1(const uint2* __restrict__ h, unsigned char* __restrict__ agg,
                          const int* __restrict__ row_ptr, const int* __restrict__ csr,
                          const float* __restrict__ inv_in) {
    int n = blockIdx.x * 4 + (threadIdx.x >> 6);
    int lane = threadIdx.x & 63;
    int s = lane >> 4;          // edge subgroup 0..3
    int off = lane & 15;        // uint2 offset within row
    f32x2 a[4];
    #pragma unroll
    for (int j = 0; j < 4; j++) a[j] = (f32x2){0.f, 0.f};
    int k0 = row_ptr[n], k1 = row_ptr[n + 1];
    int k = k0;
    for (; k + 8 <= k1; k += 8) {
        int e0 = csr[k + s], e1 = csr[k + 4 + s];
        uint2 u0 = h[(size_t)e0 * 16 + off];
        uint2 u1 = h[(size_t)e1 * 16 + off];
        a[0] += __builtin_amdgcn_cvt_pk_f32_fp8(u0.x, false)
              + __builtin_amdgcn_cvt_pk_f32_fp8(u1.x, false);
        a[1] += __builtin_amdgcn_cvt_pk_f32_fp8(u0.x, true)
              + __builtin_amdgcn_cvt_pk_f32_fp8(u1.x, true);
        a[2] += __builtin_amdgcn_cvt_pk_f32_fp8(u0.y, false)
              + __builtin_amdgcn_cvt_pk_f32_fp8(u1.y, false);
        a[3] += __builtin_amdgcn_cvt_pk_f32_fp8(u0.y, true)
              + __builtin_amdgcn_cvt_pk_f32_fp8(u1.y, true);
    }
    for (; k < k1; k += 4) {
        if (k + s < k1) {
            int e0 = csr[k + s];
            uint2 u0 = h[(size_t)e0 * 16 + off];
            a[0] += __builtin_amdgcn_cvt_pk_f32_fp8(u0.x, false);
            a[1] += __builtin_amdgcn_cvt_pk_f32_fp8(u0.x, true);
            a[2] += __builtin_amdgcn_cvt_pk_f32_fp8(u0.y, false);
            a[3] += __builtin_amdgcn_cvt_pk_f32_fp8(u0.y, true);
        }
    }
    float r[8];
    #pragma unroll
    for (int j = 0; j < 4; j++) {
        #pragma unroll
        for (int c = 0; c < 2; c++) {
            float v = a[j][c];
            r[2 * j + c] = v + __shfl(v, lane + 16, 64)
                             + __shfl(v, lane + 32, 64)
                             + __shfl(v, lane + 48, 64);
        }
    }
    if (lane < 16) {
        float wi = inv_in[n];
        int d0 = __builtin_amdgcn_cvt_pk_fp8_f32(r[0] * wi, r[1] * wi, 0, false);
        d0 = __builtin_amdgcn_cvt_pk_fp8_f32(r[2] * wi, r[3] * wi, d0, true);
        int d1 = __builtin_amdgcn_cvt_pk_fp8_f32(r[4] * wi, r[5] * wi, 0, false);
        d1 = __builtin_amdgcn_cvt_pk_fp8_f32(r[6] * wi, r[7] * wi, d1, true);
        uint2 st; st.x = (unsigned)d0; st.y = (unsigned)d1;
        *(uint2*)(agg + (size_t)n * 128 + lane * 8) = st;
    }
}

// ------- SpMM layers 2/3: 3 edges/gather (20 lanes x uint4) -> fp8 out --------
// Q8 rows 320 B = 20 uint4; pad cols 304-319 are zero. P8 rows 320 B.
__global__ void k_spmm_big(const uint4* __restrict__ h, unsigned char* __restrict__ agg,
                           const int* __restrict__ row_ptr, const int* __restrict__ csr,
                           const float* __restrict__ inv_in) {
    int n = blockIdx.x * 4 + (threadIdx.x >> 6);
    int lane = threadIdx.x & 63;
    int s = lane / 20;          // 0..2 (lanes 60-63: s=3, results dropped)
    int off = lane % 20;
    f32x2 a[8];
    #pragma unroll
    for (int j = 0; j < 8; j++) a[j] = (f32x2){0.f, 0.f};
    int k0 = row_ptr[n], k1 = row_ptr[n + 1];
    int k = k0;
    for (; k + 12 <= k1; k += 12) {
        int e0 = csr[k + s], e1 = csr[k + 3 + s], e2 = csr[k + 6 + s], e3 = csr[k + 9 + s];
        uint4 u0 = h[(size_t)e0 * 20 + off];
        uint4 u1 = h[(size_t)e1 * 20 + off];
        uint4 u2 = h[(size_t)e2 * 20 + off];
        uint4 u3 = h[(size_t)e3 * 20 + off];
        a[0] += __builtin_amdgcn_cvt_pk_f32_fp8(u0.x, false) + __builtin_amdgcn_cvt_pk_f32_fp8(u1.x, false)
              + __builtin_amdgcn_cvt_pk_f32_fp8(u2.x, false) + __builtin_amdgcn_cvt_pk_f32_fp8(u3.x, false);
        a[1] += __builtin_amdgcn_cvt_pk_f32_fp8(u0.x, true)  + __builtin_amdgcn_cvt_pk_f32_fp8(u1.x, true)
              + __builtin_amdgcn_cvt_pk_f32_fp8(u2.x, true)  + __builtin_amdgcn_cvt_pk_f32_fp8(u3.x, true);
        a[2] += __builtin_amdgcn_cvt_pk_f32_fp8(u0.y, false) + __builtin_amdgcn_cvt_pk_f32_fp8(u1.y, false)
              + __builtin_amdgcn_cvt_pk_f32_fp8(u2.y, false) + __builtin_amdgcn_cvt_pk_f32_fp8(u3.y, false);
        a[3] += __builtin_amdgcn_cvt_pk_f32_fp8(u0.y, true)  + __builtin_amdgcn_cvt_pk_f32_fp8(u1.y, true)
              + __builtin_amdgcn_cvt_pk_f32_fp8(u2.y, true)  + __builtin_amdgcn_cvt_pk_f32_fp8(u3.y, true);
        a[4] += __builtin_amdgcn_cvt_pk_f32_fp8(u0.z, false) + __builtin_amdgcn_cvt_pk_f32_fp8(u1.z, false)
              + __builtin_amdgcn_cvt_pk_f32_fp8(u2.z, false) + __builtin_amdgcn_cvt_pk_f32_fp8(u3.z, false);
        a[5] += __builtin_amdgcn_cvt_pk_f32_fp8(u0.z, true)  + __builtin_amdgcn_cvt_pk_f32_fp8(u1.z, true)
              + __builtin_amdgcn_cvt_pk_f32_fp8(u2.z, true)  + __builtin_amdgcn_cvt_pk_f32_fp8(u3.z, true);
        a[6] += __builtin_amdgcn_cvt_pk_f32_fp8(u0.w, false) + __builtin_amdgcn_cvt_pk_f32_fp8(u1.w, false)
              + __builtin_amdgcn_cvt_pk_f32_fp8(u2.w, false) + __builtin_amdgcn_cvt_pk_f32_fp8(u3.w, false);
        a[7] += __builtin_amdgcn_cvt_pk_f32_fp8(u0.w, true)  + __builtin_amdgcn_cvt_pk_f32_fp8(u1.w, true)
              + __builtin_amdgcn_cvt_pk_f32_fp8(u2.w, true)  + __builtin_amdgcn_cvt_pk_f32_fp8(u3.w, true);
    }
    for (; k < k1; k += 3) {
        if (k + s < k1) {
            int e0 = csr[k + s];
            uint4 u0 = h[(size_t)e0 * 20 + off];
            a[0] += __builtin_amdgcn_cvt_pk_f32_fp8(u0.x, false);
            a[1] += __builtin_amdgcn_cvt_pk_f32_fp8(u0.x, true);
            a[2] += __builtin_amdgcn_cvt_pk_f32_fp8(u0.y, false);
            a[3] += __builtin_amdgcn_cvt_pk_f32_fp8(u0.y, true);
            a[4] += __builtin_amdgcn_cvt_pk_f32_fp8(u0.z, false);
            a[5] += __builtin_amdgcn_cvt_pk_f32_fp8(u0.z, true);
            a[6] += __builtin_amdgcn_cvt_pk_f32_fp8(u0.w, false);
            a[7] += __builtin_amdgcn_cvt_pk_f32_fp8(u0.w, true);
        }
    }
    float r[16];
    #pragma unroll
    for (int j = 0; j < 8; j++) {
        #pragma unroll
        for (int c = 0; c < 2; c++) {
            float v = a[j][c];
            r[2 * j + c] = v + __shfl(v, lane + 20, 64) + __shfl(v, lane + 40, 64);
        }
    }
    if (lane < 20) {
        float wi = inv_in[n];
        int d0 = __builtin_amdgcn_cvt_pk_fp8_f32(r[0] * wi, r[1] * wi, 0, false);
        d0 = __builtin_amdgcn_cvt_pk_fp8_f32(r[2] * wi, r[3] * wi, d0, true);
        int d1 = __builtin_amdgcn_cvt_pk_fp8_f32(r[4] * wi, r[5] * wi, 0, false);
        d1 = __builtin_amdgcn_cvt_pk_fp8_f32(r[6] * wi, r[7] * wi, d1, true);
        int d2 = __builtin_amdgcn_cvt_pk_fp8_f32(r[8] * wi, r[9] * wi, 0, false);
        d2 = __builtin_amdgcn_cvt_pk_fp8_f32(r[10] * wi, r[11] * wi, d2, true);
        int d3 = __builtin_amdgcn_cvt_pk_fp8_f32(r[12] * wi, r[13] * wi, 0, false);
        d3 = __builtin_amdgcn_cvt_pk_fp8_f32(r[14] * wi, r[15] * wi, d3, true);
        uint4 st; st.x = (unsigned)d0; st.y = (unsigned)d1; st.z = (unsigned)d2; st.w = (unsigned)d3;
        *(uint4*)(agg + (size_t)n * 320 + lane * 16) = st;
    }
}

// ------- W prep (all 3): fp32 W[K][304] -> fp8 Wt[304][Kpad], zero-padded K ----
__global__ void k_prepw_all(const float* __restrict__ W1, const float* __restrict__ W2,
                            const float* __restrict__ W3,
                            unsigned char* __restrict__ Wt1, unsigned char* __restrict__ Wt2,
                            unsigned char* __restrict__ Wt3) {
    const int N1 = D_H * 128, N2 = D_H * 320;
    int id = blockIdx.x * 256 + threadIdx.x;
    const float* W; unsigned char* Wt; int K, Kpad, lid;
    if (id < N1)                { W = W1; Wt = Wt1; K = 128; Kpad = 128; lid = id; }
    else if (id < N1 + N2)      { W = W2; Wt = Wt2; K = 304; Kpad = 320; lid = id - N1; }
    else if (id < N1 + 2 * N2)  { W = W3; Wt = Wt3; K = 304; Kpad = 320; lid = id - N1 - N2; }
    else return;
    int n = lid / Kpad, k = lid - n * Kpad;
    unsigned char v = 0;
    if (k < K) {
        float w = W[k * D_H + n];
        v = (unsigned char)(__builtin_amdgcn_cvt_pk_fp8_f32(w, w, 0, false) & 0xff);
    }
    Wt[lid] = v;
}

// ------- fp8 MFMA GEMM, BK=64B, global_load_lds staging, LDS-packed epilogue ----
// A fp8 (lda bytes/row), Wt fp8 [304][K] bytes. K in bytes, multiple of 64.
// MODE 0: relu -> *inv_out -> fp8 packed rows (stride 320 B) to C8 (ghost rows ok)
// MODE 1: relu -> column max-pool -> atomicMax gpool
template <int MODE>
__global__ __launch_bounds__(256, 2) void k_gemm_mfma(
    const unsigned char* __restrict__ A, int lda,
    const unsigned char* __restrict__ Wt,
    const float* __restrict__ bias,
    const float* __restrict__ inv_out,
    unsigned char* __restrict__ C8, int* __restrict__ gpool, int M, int K) {
    __shared__ char SM[40960];       // As 8 KB | Bs 19 KB ; reused as 40 KB out buf
    __shared__ int pmax[D_H];
    char* As = SM;                    // 128 rows x 64 B
    char* Bs = SM + 8192;             // 304 rows x 64 B
    int tid = threadIdx.x;
    int wv = tid >> 6, lane = tid & 63;
    int quad = lane >> 4, lrow = lane & 15;
    int bm = blockIdx.x * 128;

    if (MODE == 1) {
        for (int i = tid; i < D_H; i += 256) pmax[i] = 0;
    }

    f32x4 acc[2][19];
    #pragma unroll
    for (int r = 0; r < 2; r++)
        #pragma unroll
        for (int t = 0; t < 19; t++) acc[r][t] = (f32x4){0.f, 0.f, 0.f, 0.f};

    for (int kt = 0; kt < K; kt += 64) {
        // A tile: 128 rows x 64 B = 512 16B chunks
        #pragma unroll
        for (int j = 0; j < 2; j++) {
            int c = j * 256 + tid;
            int row = c >> 2, col = c & 3;
            gload16(A + (size_t)(bm + row) * lda + kt + col * 16, As + c * 16);
        }
        // B tile: 304 rows x 64 B = 1216 chunks
        #pragma unroll
        for (int j = 0; j < 5; j++) {
            int c = j * 256 + tid;
            if (c < 1216) {
                int row = c >> 2, col = c & 3;
                gload16(Wt + (size_t)row * K + kt + col * 16, Bs + c * 16);
            }
        }
        __syncthreads();
        #pragma unroll
        for (int sub = 0; sub < 2; sub++) {
            long long a0 = *(const long long*)(As + (wv * 32 + lrow) * 64 + sub * 32 + quad * 8);
            long long a1 = *(const long long*)(As + (wv * 32 + 16 + lrow) * 64 + sub * 32 + quad * 8);
            #pragma unroll
            for (int t = 0; t < 19; t++) {
                long long b = *(const long long*)(Bs + (t * 16 + lrow) * 64 + sub * 32 + quad * 8);
                acc[0][t] = __builtin_amdgcn_mfma_f32_16x16x32_fp8_fp8(a0, b, acc[0][t], 0, 0, 0);
                acc[1][t] = __builtin_amdgcn_mfma_f32_16x16x32_fp8_fp8(a1, b, acc[1][t], 0, 0, 0);
            }
        }
        __syncthreads();
    }
    // epilogue: C/D layout col=lane&15, row=(lane>>4)*4+reg
    if (MODE == 0) {
        unsigned char* OUT = (unsigned char*)SM;   // 128 x 320 B = 40960 B
        if (tid < 128) *(uint4*)(OUT + tid * 320 + 304) = make_uint4(0u, 0u, 0u, 0u);
        #pragma unroll
        for (int t = 0; t < 19; t++) {
            int col = t * 16 + lrow;
            float bv = bias[col];
            #pragma unroll
            for (int r = 0; r < 2; r++) {
                int rl = wv * 32 + r * 16 + quad * 4;
                #pragma unroll
                for (int g = 0; g < 4; g++) {
                    int row = bm + rl + g;
                    float sc = inv_out[min(row, M - 1)];
                    float v = fmaxf(acc[r][t][g] + bv, 0.f) * sc;
                    int p = __builtin_amdgcn_cvt_pk_fp8_f32(v, v, 0, false);
                    OUT[(rl + g) * 320 + col] = (unsigned char)(p & 0xff);
                }
            }
        }
        __syncthreads();
        #pragma unroll
        for (int j = 0; j < 10; j++) {
            int c = j * 256 + tid;
            *(uint4*)(C8 + (size_t)bm * 320 + (size_t)c * 16) = *(const uint4*)(OUT + c * 16);
        }
    } else {
        #pragma unroll
        for (int t = 0; t < 19; t++) {
            int col = t * 16 + lrow;
            float bv = bias[col];
            float m = 0.f;
            #pragma unroll
            for (int r = 0; r < 2; r++) {
                int rbase = bm + wv * 32 + r * 16 + quad * 4;
                #pragma unroll
                for (int g = 0; g < 4; g++) {
                    int row = rbase + g;
                    if (row < M) m = fmaxf(m, fmaxf(acc[r][t][g] + bv, 0.f));
                }
            }
            atomicMax(&pmax[col], __float_as_int(m));
        }
        __syncthreads();
        for (int i = tid; i < D_H; i += 256)
            atomicMax(&gpool[i], pmax[i]);
    }
}

// ---------------- MLP head: 304 -> 128 -> 64 -> 1, sigmoid ----------------
__global__ void k_mlp(const int* __restrict__ pooled_i,
                      const float* __restrict__ fW1, const float* __restrict__ fb1,
                      const float* __restrict__ fW2, const float* __restrict__ fb2,
                      const float* __restrict__ fW3, const float* __restrict__ fb3,
                      float* __restrict__ out) {
    __shared__ float p[D_H];
    __shared__ float z1[128];
    __shared__ float z2[64];
    int t = threadIdx.x;  // 320
    if (t < D_H) p[t] = __int_as_float(pooled_i[t]);
    __syncthreads();
    if (t < 128) {
        float acc = fb1[t];
        for (int k = 0; k < D_H; k++) acc += p[k] * fW1[k * 128 + t];
        z1[t] = fmaxf(acc, 0.f);
    }
    __syncthreads();
    if (t < 64) {
        float acc = fb2[t];
        for (int k = 0; k < 128; k++) acc += z1[k] * fW2[k * 64 + t];
        z2[t] = fmaxf(acc, 0.f);
    }
    __syncthreads();
    if (t == 0) {
        float acc = fb3[0];
        for (int k = 0; k < 64; k++) acc += z2[k] * fW3[k];
        out[0] = 1.f / (1.f + expf(-acc));
    }
}

extern "C" void kernel_launch(void* const* d_in, const int* in_sizes, int n_in,
                              void* d_out, int out_size, void* d_ws, size_t ws_size,
                              hipStream_t stream) {
    const float* x1 = (const float*)d_in[0];
    const float* x2 = (const float*)d_in[1];
    const float* x3 = (const float*)d_in[2];
    const int* src1 = (const int*)d_in[3];
    const int* dst1 = (const int*)d_in[4];
    const int* src2 = (const int*)d_in[5];
    const int* dst2 = (const int*)d_in[6];
    const int* src3 = (const int*)d_in[7];
    const int* dst3 = (const int*)d_in[8];
    const float* W1 = (const float*)d_in[9];
    const float* b1 = (const float*)d_in[10];
    const float* W2 = (const float*)d_in[11];
    const float* b2 = (const float*)d_in[12];
    const float* W3 = (const float*)d_in[13];
    const float* b3 = (const float*)d_in[14];
    const float* fW1 = (const float*)d_in[15];
    const float* fb1 = (const float*)d_in[16];
    const float* fW2 = (const float*)d_in[17];
    const float* fb2 = (const float*)d_in[18];
    const float* fW3 = (const float*)d_in[19];
    const float* fb3 = (const float*)d_in[20];
    float* out = (float*)d_out;

    char* w = (char*)d_ws;
    unsigned* X8       = (unsigned*)w;      w += (size_t)TOTN * 32 * 4;        // fp8 60000x128
    unsigned char* Q8  = (unsigned char*)w; w += (size_t)(TOTN + 128) * 320;   // fp8 304+16pad (+ghost)
    unsigned char* P8  = (unsigned char*)w; w += (size_t)(TOTN + 128) * 320;   // fp8 spmm out (+ghost)
    unsigned char* Wt1 = (unsigned char*)w; w += (size_t)D_H * 128;
    unsigned char* Wt2 = (unsigned char*)w; w += (size_t)D_H * 320;
    unsigned char* Wt3 = (unsigned char*)w; w += (size_t)D_H * 320;
    w = (char*)(((size_t)w + 255) & ~(size_t)255);
    int* partial_in  = (int*)w;  w += (size_t)NB * SLICES * NODES * 4;  // 9.6 MB
    int* partial_out = (int*)w;  w += (size_t)NB * SLICES * NODES * 4;
    int* O           = (int*)w;  w += (size_t)NB * SLICES * NODES * 4;
    float* inv_out = (float*)w;  w += (size_t)TOTN * 4;
    float* inv_in  = (float*)w;  w += (size_t)TOTN * 4;
    int* row_ptr   = (int*)w;    w += (size_t)(TOTN + 4) * 4;
    int* csr       = (int*)w;    w += (size_t)(TOTE + 16) * 4;          // +16 slack
    int* excl      = (int*)w;    w += (size_t)TOTN * 4;
    int* btot      = (int*)w;    w += 64 * 4;
    int* boff      = (int*)w;    w += 64 * 4;
    int* pooled    = (int*)w;    w += 320 * 4;

    k_hist<<<dim3(NB * SLICES, 2), 256, 0, stream>>>(src1, dst1, src2, dst2, src3, dst3,
                                                     partial_in, partial_out);
    k_degscan<<<SCAN_B, 1024, 0, stream>>>(partial_in, partial_out,
                                           inv_in, inv_out, excl, btot);
    k_pack8<<<(3 * NODES * D_IN / 4 + 255) / 256, 256, 0, stream>>>(
        (const float4*)x1, (const float4*)x2, (const float4*)x3, inv_out, X8);
    k_scanB<<<1, 64, 0, stream>>>(btot, boff, csr + TOTE, pooled);
    k_offC<<<(TOTN + 256) / 256, 256, 0, stream>>>(excl, boff, partial_in, row_ptr, O);
    k_fill2<<<NB * SLICES, 256, 0, stream>>>(src1, dst1, src2, dst2, src3, dst3, O, csr);
    k_prepw_all<<<(D_H * (128 + 320 + 320) + 255) / 256, 256, 0, stream>>>(
        W1, W2, W3, Wt1, Wt2, Wt3);

    int ggrid = (TOTN + 127) / 128;  // 469

    // layer 1: X8(fp8*inv_out,128) -> SpMM -> P8(fp8,128B) -> GEMM(K=128) -> Q8
    k_spmm_l1<<<TOTN / 4, 256, 0, stream>>>((const uint2*)X8, P8, row_ptr, csr, inv_in);
    k_gemm_mfma<0><<<ggrid, 256, 0, stream>>>(P8, 128, Wt1, b1, inv_out,
                                              Q8, nullptr, TOTN, 128);
    // layer 2
    k_spmm_big<<<TOTN / 4, 256, 0, stream>>>((const uint4*)Q8, P8, row_ptr, csr, inv_in);
    k_gemm_mfma<0><<<ggrid, 256, 0, stream>>>(P8, 320, Wt2, b2, inv_out,
                                              Q8, nullptr, TOTN, 320);
    // layer 3: GEMM fused with column max-pool (no h3 materialization)
    k_spmm_big<<<TOTN / 4, 256, 0, stream>>>((const uint4*)Q8, P8, row_ptr, csr, inv_in);
    k_gemm_mfma<1><<<ggrid, 256, 0, stream>>>(P8, 320, Wt3, b3, nullptr,
                                              nullptr, pooled, TOTN, 320);

    k_mlp<<<1, 320, 0, stream>>>(pooled, fW1, fb1, fW2, fb2, fW3, fb3, out);
}

// Round 11
// 375.371 us; speedup vs baseline: 1.1081x; 1.1081x over previous
//
#include <hip/hip_runtime.h>
#include <hip/hip_bf16.h>
#include <math.h>

#define NODES 20000
#define EDGES 320000
#define NB 3
#define TOTN (NODES * NB)   // 60000
#define TOTE (EDGES * NB)   // 960000
#define D_IN 128
#define D_H 304
#define SCAN_B 59           // ceil(60000/1024)
#define SLICES 40
#define SLICE_E (EDGES / SLICES)   // 8000

typedef __attribute__((ext_vector_type(4))) float f32x4;
typedef __attribute__((ext_vector_type(2))) float f32x2;

__device__ __forceinline__ unsigned short f2bf(float f) {
    unsigned u = __float_as_uint(f);
    unsigned r = (u + 0x7fffu + ((u >> 16) & 1u)) >> 16;   // RNE
    return (unsigned short)r;
}
// async global->LDS, 16 B per lane; LDS dst must be wave-uniform base + lane*16
__device__ __forceinline__ void gload16(const void* g, void* l) {
    __builtin_amdgcn_global_load_lds(
        (const __attribute__((address_space(1))) unsigned*)g,
        (__attribute__((address_space(3))) unsigned*)l, 16, 0, 0);
}

// ------- pack x1|x2|x3 fp32 -> X fp8 (60000 x 128), pre-scaled by inv_out -------
__global__ void k_pack8(const float4* __restrict__ x1, const float4* __restrict__ x2,
                        const float4* __restrict__ x3, const float* __restrict__ inv_out,
                        unsigned* __restrict__ q) {
    const int per = NODES * D_IN / 4;  // out dwords per graph (32 per row)
    int i = blockIdx.x * 256 + threadIdx.x;
    if (i >= 3 * per) return;
    const float4* s; int j;
    if (i < per)          { s = x1; j = i; }
    else if (i < 2 * per) { s = x2; j = i - per; }
    else                  { s = x3; j = i - 2 * per; }
    float4 v = s[j];
    float sc = inv_out[i >> 5];   // 32 dwords per row, global node id
    int p = __builtin_amdgcn_cvt_pk_fp8_f32(v.x * sc, v.y * sc, 0, false);
    p = __builtin_amdgcn_cvt_pk_fp8_f32(v.z * sc, v.w * sc, p, true);
    q[i] = (unsigned)p;
}

// ------- per-(graph,slice) LDS histograms: no global atomics -------
__global__ __launch_bounds__(256, 1) void k_hist(
    const int* __restrict__ s1, const int* __restrict__ d1,
    const int* __restrict__ s2, const int* __restrict__ d2,
    const int* __restrict__ s3, const int* __restrict__ d3,
    int* __restrict__ partial_in, int* __restrict__ partial_out) {
    __shared__ int hist[NODES];   // 80 KB
    int g = blockIdx.x / SLICES, s = blockIdx.x % SLICES;
    bool isOut = (blockIdx.y == 1);
    const int* ep;
    if (isOut) ep = (g == 0) ? s1 : ((g == 1) ? s2 : s3);
    else       ep = (g == 0) ? d1 : ((g == 1) ? d2 : d3);
    ep += s * SLICE_E;
    for (int i = threadIdx.x; i < NODES; i += 256) hist[i] = 0;
    __syncthreads();
    const int4* ep4 = (const int4*)ep;
    for (int i = threadIdx.x; i < SLICE_E / 4; i += 256) {
        int4 v = ep4[i];
        atomicAdd(&hist[v.x], 1);
        atomicAdd(&hist[v.y], 1);
        atomicAdd(&hist[v.z], 1);
        atomicAdd(&hist[v.w], 1);
    }
    __syncthreads();
    int* po = (isOut ? partial_out : partial_in) + (size_t)blockIdx.x * NODES;
    for (int i = threadIdx.x; i < NODES; i += 256) po[i] = hist[i];
}

// ------- degrees from partials + inv factors + block-level scan (fused) -------
__global__ void k_degscan(const int* __restrict__ partial_in,
                          const int* __restrict__ partial_out,
                          float* __restrict__ inv_in, float* __restrict__ inv_out,
                          int* __restrict__ excl, int* __restrict__ btot) {
    __shared__ int wsum[16];
    int b = blockIdx.x, t = threadIdx.x;
    int i = b * 1024 + t;
    int lane = t & 63, wid = t >> 6;
    int v = 0;
    if (i < TOTN) {
        int g = i / NODES, ln = i - g * NODES;
        const int* pi = partial_in + (size_t)g * SLICES * NODES + ln;
        const int* po = partial_out + (size_t)g * SLICES * NODES + ln;
        int ci = 0, co = 0;
        #pragma unroll
        for (int s = 0; s < SLICES; s++) { ci += pi[s * NODES]; co += po[s * NODES]; }
        v = ci;
        inv_in[i]  = 1.0f / sqrtf((float)max(ci, 1));
        inv_out[i] = 1.0f / sqrtf((float)max(co, 1));
    }
    int sv = v;
    #pragma unroll
    for (int o = 1; o < 64; o <<= 1) {
        int u = __shfl_up(sv, o, 64);
        if (lane >= o) sv += u;
    }
    if (lane == 63) wsum[wid] = sv;
    __syncthreads();
    if (t < 16) {
        int w = wsum[t];
        #pragma unroll
        for (int o = 1; o < 16; o <<= 1) {
            int u = __shfl_up(w, o, 16);
            if (t >= o) w += u;
        }
        wsum[t] = w;
    }
    __syncthreads();
    int wbase = (wid > 0) ? wsum[wid - 1] : 0;
    if (i < TOTN) excl[i] = wbase + sv - v;
    if (t == 0) btot[b] = wsum[15];
}

// ------- scan of block totals + zero pooled + zero csr slack (fused) -------
__global__ void k_scanB(const int* __restrict__ btot, int* __restrict__ boff,
                        int* __restrict__ csr_slack, int* __restrict__ pooled) {
    int t = threadIdx.x;  // 64
    if (t < 16) csr_slack[t] = 0;   // zero csr[TOTE..TOTE+15] over-read slack
    #pragma unroll
    for (int i = t; i < 320; i += 64) pooled[i] = 0;
    int v = (t < SCAN_B) ? btot[t] : 0;
    int sv = v;
    #pragma unroll
    for (int o = 1; o < 64; o <<= 1) {
        int u = __shfl_up(sv, o, 64);
        if (t >= o) sv += u;
    }
    if (t < SCAN_B) boff[t] = sv - v;  // exclusive
}

// ------- row_ptr apply + per-(slice,node) CSR base offsets (fused) -------
__global__ void k_offC(const int* __restrict__ excl, const int* __restrict__ boff,
                       const int* __restrict__ partial_in,
                       int* __restrict__ row_ptr, int* __restrict__ O) {
    int n = blockIdx.x * 256 + threadIdx.x;
    if (n >= TOTN) {
        if (n == TOTN) row_ptr[TOTN] = TOTE;
        return;
    }
    if (n == 0) row_ptr[TOTN] = TOTE;
    int rp = excl[n] + boff[n >> 10];
    row_ptr[n] = rp;
    int g = n / NODES, ln = n - g * NODES;
    const int* pi = partial_in + (size_t)g * SLICES * NODES + ln;
    int* on = O + (size_t)g * SLICES * NODES + ln;
    int run = rp;
    #pragma unroll
    for (int s = 0; s < SLICES; s++) {
        on[s * NODES] = run;
        run += pi[s * NODES];
    }
}

// ------- CSR fill via LDS cursors (global-atomic-free) -------
__global__ __launch_bounds__(256, 1) void k_fill2(
    const int* __restrict__ s1, const int* __restrict__ d1,
    const int* __restrict__ s2, const int* __restrict__ d2,
    const int* __restrict__ s3, const int* __restrict__ d3,
    const int* __restrict__ O, int* __restrict__ csr) {
    __shared__ int cur[NODES];   // 80 KB
    int g = blockIdx.x / SLICES, s = blockIdx.x % SLICES;
    const int* sp = (g == 0) ? s1 : ((g == 1) ? s2 : s3);
    const int* dp = (g == 0) ? d1 : ((g == 1) ? d2 : d3);
    sp += s * SLICE_E; dp += s * SLICE_E;
    const int* on = O + (size_t)blockIdx.x * NODES;
    for (int i = threadIdx.x; i < NODES; i += 256) cur[i] = on[i];
    __syncthreads();
    int base = g * NODES;
    const int4* sp4 = (const int4*)sp;
    const int4* dp4 = (const int4*)dp;
    for (int i = threadIdx.x; i < SLICE_E / 4; i += 256) {
        int4 dv = dp4[i];
        int4 sv = sp4[i];
        int p0 = atomicAdd(&cur[dv.x], 1); csr[p0] = sv.x + base;
        int p1 = atomicAdd(&cur[dv.y], 1); csr[p1] = sv.y + base;
        int p2 = atomicAdd(&cur[dv.z], 1); csr[p2] = sv.z + base;
        int p3 = atomicAdd(&cur[dv.w], 1); csr[p3] = sv.w + base;
    }
}

// ------- SpMM layer 1: 4 edges/gather (16 lanes x uint2) -> fp8 out ----------
// X8 rows: 128 fp8 = 16 uint2. One node per wave. P8 rows 128 B.
__global__ void k_spmm_l1(const uint2* __restrict__ h, unsigned char* __restrict__ agg,
                          const int* __restrict__ row_ptr, const int* __restrict__ csr,
                          const float* __restrict__ inv_in) {
    int n = blockIdx.x * 4 + (threadIdx.x >> 6);
    int lane = threadIdx.x & 63;
    int s = lane >> 4;          // edge subgroup 0..3
    int off = lane & 15;        // uint2 offset within row
    f32x2 a[4];
    #pragma unroll
    for (int j = 0; j < 4; j++) a[j] = (f32x2){0.f, 0.f};
    int k0 = row_ptr[n], k1 = row_ptr[n + 1];
    int k = k0;
    for (; k + 8 <= k1; k += 8) {
        int e0 = csr[k + s], e1 = csr[k + 4 + s];
        uint2 u0 = h[(size_t)e0 * 16 + off];
        uint2 u1 = h[(size_t)e1 * 16 + off];
        a[0] += __builtin_amdgcn_cvt_pk_f32_fp8(u0.x, false)
              + __builtin_amdgcn_cvt_pk_f32_fp8(u1.x, false);
        a[1] += __builtin_amdgcn_cvt_pk_f32_fp8(u0.x, true)
              + __builtin_amdgcn_cvt_pk_f32_fp8(u1.x, true);
        a[2] += __builtin_amdgcn_cvt_pk_f32_fp8(u0.y, false)
              + __builtin_amdgcn_cvt_pk_f32_fp8(u1.y, false);
        a[3] += __builtin_amdgcn_cvt_pk_f32_fp8(u0.y, true)
              + __builtin_amdgcn_cvt_pk_f32_fp8(u1.y, true);
    }
    for (; k < k1; k += 4) {
        if (k + s < k1) {
            int e0 = csr[k + s];
            uint2 u0 = h[(size_t)e0 * 16 + off];
            a[0] += __builtin_amdgcn_cvt_pk_f32_fp8(u0.x, false);
            a[1] += __builtin_amdgcn_cvt_pk_f32_fp8(u0.x, true);
            a[2] += __builtin_amdgcn_cvt_pk_f32_fp8(u0.y, false);
            a[3] += __builtin_amdgcn_cvt_pk_f32_fp8(u0.y, true);
        }
    }
    float r[8];
    #pragma unroll
    for (int j = 0; j < 4; j++) {
        #pragma unroll
        for (int c = 0; c < 2; c++) {
            float v = a[j][c];
            r[2 * j + c] = v + __shfl(v, lane + 16, 64)
                             + __shfl(v, lane + 32, 64)
                             + __shfl(v, lane + 48, 64);
        }
    }
    if (lane < 16) {
        float wi = inv_in[n];
        int d0 = __builtin_amdgcn_cvt_pk_fp8_f32(r[0] * wi, r[1] * wi, 0, false);
        d0 = __builtin_amdgcn_cvt_pk_fp8_f32(r[2] * wi, r[3] * wi, d0, true);
        int d1 = __builtin_amdgcn_cvt_pk_fp8_f32(r[4] * wi, r[5] * wi, 0, false);
        d1 = __builtin_amdgcn_cvt_pk_fp8_f32(r[6] * wi, r[7] * wi, d1, true);
        uint2 st; st.x = (unsigned)d0; st.y = (unsigned)d1;
        *(uint2*)(agg + (size_t)n * 128 + lane * 8) = st;
    }
}

// ------- SpMM layers 2/3: 3 edges/gather (20 lanes x uint4) -> fp8 out --------
// Q8 rows 320 B = 20 uint4; pad cols 304-319 are zero. P8 rows 320 B.
__global__ void k_spmm_big(const uint4* __restrict__ h, unsigned char* __restrict__ agg,
                           const int* __restrict__ row_ptr, const int* __restrict__ csr,
                           const float* __restrict__ inv_in) {
    int n = blockIdx.x * 4 + (threadIdx.x >> 6);
    int lane = threadIdx.x & 63;
    int s = lane / 20;          // 0..2 (lanes 60-63: s=3, results dropped)
    int off = lane % 20;
    f32x2 a[8];
    #pragma unroll
    for (int j = 0; j < 8; j++) a[j] = (f32x2){0.f, 0.f};
    int k0 = row_ptr[n], k1 = row_ptr[n + 1];
    int k = k0;
    for (; k + 12 <= k1; k += 12) {
        int e0 = csr[k + s], e1 = csr[k + 3 + s], e2 = csr[k + 6 + s], e3 = csr[k + 9 + s];
        uint4 u0 = h[(size_t)e0 * 20 + off];
        uint4 u1 = h[(size_t)e1 * 20 + off];
        uint4 u2 = h[(size_t)e2 * 20 + off];
        uint4 u3 = h[(size_t)e3 * 20 + off];
        a[0] += __builtin_amdgcn_cvt_pk_f32_fp8(u0.x, false) + __builtin_amdgcn_cvt_pk_f32_fp8(u1.x, false)
              + __builtin_amdgcn_cvt_pk_f32_fp8(u2.x, false) + __builtin_amdgcn_cvt_pk_f32_fp8(u3.x, false);
        a[1] += __builtin_amdgcn_cvt_pk_f32_fp8(u0.x, true)  + __builtin_amdgcn_cvt_pk_f32_fp8(u1.x, true)
              + __builtin_amdgcn_cvt_pk_f32_fp8(u2.x, true)  + __builtin_amdgcn_cvt_pk_f32_fp8(u3.x, true);
        a[2] += __builtin_amdgcn_cvt_pk_f32_fp8(u0.y, false) + __builtin_amdgcn_cvt_pk_f32_fp8(u1.y, false)
              + __builtin_amdgcn_cvt_pk_f32_fp8(u2.y, false) + __builtin_amdgcn_cvt_pk_f32_fp8(u3.y, false);
        a[3] += __builtin_amdgcn_cvt_pk_f32_fp8(u0.y, true)  + __builtin_amdgcn_cvt_pk_f32_fp8(u1.y, true)
              + __builtin_amdgcn_cvt_pk_f32_fp8(u2.y, true)  + __builtin_amdgcn_cvt_pk_f32_fp8(u3.y, true);
        a[4] += __builtin_amdgcn_cvt_pk_f32_fp8(u0.z, false) + __builtin_amdgcn_cvt_pk_f32_fp8(u1.z, false)
              + __builtin_amdgcn_cvt_pk_f32_fp8(u2.z, false) + __builtin_amdgcn_cvt_pk_f32_fp8(u3.z, false);
        a[5] += __builtin_amdgcn_cvt_pk_f32_fp8(u0.z, true)  + __builtin_amdgcn_cvt_pk_f32_fp8(u1.z, true)
              + __builtin_amdgcn_cvt_pk_f32_fp8(u2.z, true)  + __builtin_amdgcn_cvt_pk_f32_fp8(u3.z, true);
        a[6] += __builtin_amdgcn_cvt_pk_f32_fp8(u0.w, false) + __builtin_amdgcn_cvt_pk_f32_fp8(u1.w, false)
              + __builtin_amdgcn_cvt_pk_f32_fp8(u2.w, false) + __builtin_amdgcn_cvt_pk_f32_fp8(u3.w, false);
        a[7] += __builtin_amdgcn_cvt_pk_f32_fp8(u0.w, true)  + __builtin_amdgcn_cvt_pk_f32_fp8(u1.w, true)
              + __builtin_amdgcn_cvt_pk_f32_fp8(u2.w, true)  + __builtin_amdgcn_cvt_pk_f32_fp8(u3.w, true);
    }
    for (; k < k1; k += 3) {
        if (k + s < k1) {
            int e0 = csr[k + s];
            uint4 u0 = h[(size_t)e0 * 20 + off];
            a[0] += __builtin_amdgcn_cvt_pk_f32_fp8(u0.x, false);
            a[1] += __builtin_amdgcn_cvt_pk_f32_fp8(u0.x, true);
            a[2] += __builtin_amdgcn_cvt_pk_f32_fp8(u0.y, false);
            a[3] += __builtin_amdgcn_cvt_pk_f32_fp8(u0.y, true);
            a[4] += __builtin_amdgcn_cvt_pk_f32_fp8(u0.z, false);
            a[5] += __builtin_amdgcn_cvt_pk_f32_fp8(u0.z, true);
            a[6] += __builtin_amdgcn_cvt_pk_f32_fp8(u0.w, false);
            a[7] += __builtin_amdgcn_cvt_pk_f32_fp8(u0.w, true);
        }
    }
    float r[16];
    #pragma unroll
    for (int j = 0; j < 8; j++) {
        #pragma unroll
        for (int c = 0; c < 2; c++) {
            float v = a[j][c];
            r[2 * j + c] = v + __shfl(v, lane + 20, 64) + __shfl(v, lane + 40, 64);
        }
    }
    if (lane < 20) {
        float wi = inv_in[n];
        int d0 = __builtin_amdgcn_cvt_pk_fp8_f32(r[0] * wi, r[1] * wi, 0, false);
        d0 = __builtin_amdgcn_cvt_pk_fp8_f32(r[2] * wi, r[3] * wi, d0, true);
        int d1 = __builtin_amdgcn_cvt_pk_fp8_f32(r[4] * wi, r[5] * wi, 0, false);
        d1 = __builtin_amdgcn_cvt_pk_fp8_f32(r[6] * wi, r[7] * wi, d1, true);
        int d2 = __builtin_amdgcn_cvt_pk_fp8_f32(r[8] * wi, r[9] * wi, 0, false);
        d2 = __builtin_amdgcn_cvt_pk_fp8_f32(r[10] * wi, r[11] * wi, d2, true);
        int d3 = __builtin_amdgcn_cvt_pk_fp8_f32(r[12] * wi, r[13] * wi, 0, false);
        d3 = __builtin_amdgcn_cvt_pk_fp8_f32(r[14] * wi, r[15] * wi, d3, true);
        uint4 st; st.x = (unsigned)d0; st.y = (unsigned)d1; st.z = (unsigned)d2; st.w = (unsigned)d3;
        *(uint4*)(agg + (size_t)n * 320 + lane * 16) = st;
    }
}

// ------- W prep (all 3): fp32 W[K][304] -> fp8 Wt[304][Kpad], zero-padded K ----
__global__ void k_prepw_all(const float* __restrict__ W1, const float* __restrict__ W2,
                            const float* __restrict__ W3,
                            unsigned char* __restrict__ Wt1, unsigned char* __restrict__ Wt2,
                            unsigned char* __restrict__ Wt3) {
    const int N1 = D_H * 128, N2 = D_H * 320;
    int id = blockIdx.x * 256 + threadIdx.x;
    const float* W; unsigned char* Wt; int K, Kpad, lid;
    if (id < N1)                { W = W1; Wt = Wt1; K = 128; Kpad = 128; lid = id; }
    else if (id < N1 + N2)      { W = W2; Wt = Wt2; K = 304; Kpad = 320; lid = id - N1; }
    else if (id < N1 + 2 * N2)  { W = W3; Wt = Wt3; K = 304; Kpad = 320; lid = id - N1 - N2; }
    else return;
    int n = lid / Kpad, k = lid - n * Kpad;
    unsigned char v = 0;
    if (k < K) {
        float w = W[k * D_H + n];
        v = (unsigned char)(__builtin_amdgcn_cvt_pk_fp8_f32(w, w, 0, false) & 0xff);
    }
    Wt[lid] = v;
}

// ------- fp8 MFMA GEMM, BK=64B, swizzled global_load_lds staging ---------------
// LDS chunk swizzle: slot (row, xc) holds global chunk col = xc ^ (row&3) ^ ((row>>2)&3)
// -> fragment ds_read_b64 banks spread to 2 lanes/bank (free, m136).
// MODE 0: relu -> *inv_out -> fp8 packed rows (stride 320 B) to C8 (ghost rows ok)
// MODE 1: relu -> column max-pool -> atomicMax gpool
template <int MODE>
__global__ __launch_bounds__(256, 2) void k_gemm_mfma(
    const unsigned char* __restrict__ A, int lda,
    const unsigned char* __restrict__ Wt,
    const float* __restrict__ bias,
    const float* __restrict__ inv_out,
    unsigned char* __restrict__ C8, int* __restrict__ gpool, int M, int K) {
    __shared__ char SM[40960];       // As 8 KB | Bs 19 KB ; reused as 40 KB out buf
    __shared__ int pmax[D_H];
    char* As = SM;                    // 128 rows x 64 B (swizzled chunks)
    char* Bs = SM + 8192;             // 304 rows x 64 B (swizzled chunks)
    int tid = threadIdx.x;
    int wv = tid >> 6, lane = tid & 63;
    int quad = lane >> 4, lrow = lane & 15;
    int bm = blockIdx.x * 128;

    if (MODE == 1) {
        for (int i = tid; i < D_H; i += 256) pmax[i] = 0;
    }

    f32x4 acc[2][19];
    #pragma unroll
    for (int r = 0; r < 2; r++)
        #pragma unroll
        for (int t = 0; t < 19; t++) acc[r][t] = (f32x4){0.f, 0.f, 0.f, 0.f};

    int swz = (lrow & 3) ^ (lrow >> 2);     // per-lane chunk-col xor term
    int hb = (quad & 1) * 8;                // 8B half within 16B chunk

    for (int kt = 0; kt < K; kt += 64) {
        // A tile: 128 rows x 64 B = 512 16B chunks, swizzled source col
        #pragma unroll
        for (int j = 0; j < 2; j++) {
            int c = j * 256 + tid;
            int row = c >> 2, xc = c & 3;
            int col = xc ^ (row & 3) ^ ((row >> 2) & 3);
            gload16(A + (size_t)(bm + row) * lda + kt + col * 16, As + c * 16);
        }
        // B tile: 304 rows x 64 B = 1216 chunks
        #pragma unroll
        for (int j = 0; j < 5; j++) {
            int c = j * 256 + tid;
            if (c < 1216) {
                int row = c >> 2, xc = c & 3;
                int col = xc ^ (row & 3) ^ ((row >> 2) & 3);
                gload16(Wt + (size_t)row * K + kt + col * 16, Bs + c * 16);
            }
        }
        __syncthreads();
        #pragma unroll
        for (int sub = 0; sub < 2; sub++) {
            int c0 = sub * 2 + (quad >> 1);          // needed chunk col
            int cx = (c0 ^ swz) * 16 + hb;           // swizzled byte offset in row
            int ra = wv * 32 + lrow;
            long long a0 = *(const long long*)(As + ra * 64 + cx);
            long long a1 = *(const long long*)(As + (ra + 16) * 64 + cx);
            #pragma unroll
            for (int t = 0; t < 19; t++) {
                long long b = *(const long long*)(Bs + (t * 16 + lrow) * 64 + cx);
                acc[0][t] = __builtin_amdgcn_mfma_f32_16x16x32_fp8_fp8(a0, b, acc[0][t], 0, 0, 0);
                acc[1][t] = __builtin_amdgcn_mfma_f32_16x16x32_fp8_fp8(a1, b, acc[1][t], 0, 0, 0);
            }
        }
        __syncthreads();
    }
    // epilogue: C/D layout col=lane&15, row=(lane>>4)*4+reg
    if (MODE == 0) {
        unsigned char* OUT = (unsigned char*)SM;   // 128 x 320 B = 40960 B
        if (tid < 128) *(uint4*)(OUT + tid * 320 + 304) = make_uint4(0u, 0u, 0u, 0u);
        #pragma unroll
        for (int t = 0; t < 19; t++) {
            int col = t * 16 + lrow;
            float bv = bias[col];
            #pragma unroll
            for (int r = 0; r < 2; r++) {
                int rl = wv * 32 + r * 16 + quad * 4;
                #pragma unroll
                for (int g = 0; g < 4; g++) {
                    int row = bm + rl + g;
                    float sc = inv_out[min(row, M - 1)];
                    float v = fmaxf(acc[r][t][g] + bv, 0.f) * sc;
                    int p = __builtin_amdgcn_cvt_pk_fp8_f32(v, v, 0, false);
                    OUT[(rl + g) * 320 + col] = (unsigned char)(p & 0xff);
                }
            }
        }
        __syncthreads();
        #pragma unroll
        for (int j = 0; j < 10; j++) {
            int c = j * 256 + tid;
            *(uint4*)(C8 + (size_t)bm * 320 + (size_t)c * 16) = *(const uint4*)(OUT + c * 16);
        }
    } else {
        #pragma unroll
        for (int t = 0; t < 19; t++) {
            int col = t * 16 + lrow;
            float bv = bias[col];
            float m = 0.f;
            #pragma unroll
            for (int r = 0; r < 2; r++) {
                int rbase = bm + wv * 32 + r * 16 + quad * 4;
                #pragma unroll
                for (int g = 0; g < 4; g++) {
                    int row = rbase + g;
                    if (row < M) m = fmaxf(m, fmaxf(acc[r][t][g] + bv, 0.f));
                }
            }
            atomicMax(&pmax[col], __float_as_int(m));
        }
        __syncthreads();
        for (int i = tid; i < D_H; i += 256)
            atomicMax(&gpool[i], pmax[i]);
    }
}

// ---------------- MLP head: 304 -> 128 -> 64 -> 1, sigmoid ----------------
__global__ void k_mlp(const int* __restrict__ pooled_i,
                      const float* __restrict__ fW1, const float* __restrict__ fb1,
                      const float* __restrict__ fW2, const float* __restrict__ fb2,
                      const float* __restrict__ fW3, const float* __restrict__ fb3,
                      float* __restrict__ out) {
    __shared__ float p[D_H];
    __shared__ float z1[128];
    __shared__ float z2[64];
    int t = threadIdx.x;  // 320
    if (t < D_H) p[t] = __int_as_float(pooled_i[t]);
    __syncthreads();
    if (t < 128) {
        float acc = fb1[t];
        for (int k = 0; k < D_H; k++) acc += p[k] * fW1[k * 128 + t];
        z1[t] = fmaxf(acc, 0.f);
    }
    __syncthreads();
    if (t < 64) {
        float acc = fb2[t];
        for (int k = 0; k < 128; k++) acc += z1[k] * fW2[k * 64 + t];
        z2[t] = fmaxf(acc, 0.f);
    }
    __syncthreads();
    if (t == 0) {
        float acc = fb3[0];
        for (int k = 0; k < 64; k++) acc += z2[k] * fW3[k];
        out[0] = 1.f / (1.f + expf(-acc));
    }
}

extern "C" void kernel_launch(void* const* d_in, const int* in_sizes, int n_in,
                              void* d_out, int out_size, void* d_ws, size_t ws_size,
                              hipStream_t stream) {
    const float* x1 = (const float*)d_in[0];
    const float* x2 = (const float*)d_in[1];
    const float* x3 = (const float*)d_in[2];
    const int* src1 = (const int*)d_in[3];
    const int* dst1 = (const int*)d_in[4];
    const int* src2 = (const int*)d_in[5];
    const int* dst2 = (const int*)d_in[6];
    const int* src3 = (const int*)d_in[7];
    const int* dst3 = (const int*)d_in[8];
    const float* W1 = (const float*)d_in[9];
    const float* b1 = (const float*)d_in[10];
    const float* W2 = (const float*)d_in[11];
    const float* b2 = (const float*)d_in[12];
    const float* W3 = (const float*)d_in[13];
    const float* b3 = (const float*)d_in[14];
    const float* fW1 = (const float*)d_in[15];
    const float* fb1 = (const float*)d_in[16];
    const float* fW2 = (const float*)d_in[17];
    const float* fb2 = (const float*)d_in[18];
    const float* fW3 = (const float*)d_in[19];
    const float* fb3 = (const float*)d_in[20];
    float* out = (float*)d_out;

    char* w = (char*)d_ws;
    unsigned* X8       = (unsigned*)w;      w += (size_t)TOTN * 32 * 4;        // fp8 60000x128
    unsigned char* Q8  = (unsigned char*)w; w += (size_t)(TOTN + 128) * 320;   // fp8 304+16pad (+ghost)
    unsigned char* P8  = (unsigned char*)w; w += (size_t)(TOTN + 128) * 320;   // fp8 spmm out (+ghost)
    unsigned char* Wt1 = (unsigned char*)w; w += (size_t)D_H * 128;
    unsigned char* Wt2 = (unsigned char*)w; w += (size_t)D_H * 320;
    unsigned char* Wt3 = (unsigned char*)w; w += (size_t)D_H * 320;
    w = (char*)(((size_t)w + 255) & ~(size_t)255);
    int* partial_in  = (int*)w;  w += (size_t)NB * SLICES * NODES * 4;  // 9.6 MB
    int* partial_out = (int*)w;  w += (size_t)NB * SLICES * NODES * 4;
    int* O           = (int*)w;  w += (size_t)NB * SLICES * NODES * 4;
    float* inv_out = (float*)w;  w += (size_t)TOTN * 4;
    float* inv_in  = (float*)w;  w += (size_t)TOTN * 4;
    int* row_ptr   = (int*)w;    w += (size_t)(TOTN + 4) * 4;
    int* csr       = (int*)w;    w += (size_t)(TOTE + 16) * 4;          // +16 slack
    int* excl      = (int*)w;    w += (size_t)TOTN * 4;
    int* btot      = (int*)w;    w += 64 * 4;
    int* boff      = (int*)w;    w += 64 * 4;
    int* pooled    = (int*)w;    w += 320 * 4;

    k_hist<<<dim3(NB * SLICES, 2), 256, 0, stream>>>(src1, dst1, src2, dst2, src3, dst3,
                                                     partial_in, partial_out);
    k_degscan<<<SCAN_B, 1024, 0, stream>>>(partial_in, partial_out,
                                           inv_in, inv_out, excl, btot);
    k_pack8<<<(3 * NODES * D_IN / 4 + 255) / 256, 256, 0, stream>>>(
        (const float4*)x1, (const float4*)x2, (const float4*)x3, inv_out, X8);
    k_scanB<<<1, 64, 0, stream>>>(btot, boff, csr + TOTE, pooled);
    k_offC<<<(TOTN + 256) / 256, 256, 0, stream>>>(excl, boff, partial_in, row_ptr, O);
    k_fill2<<<NB * SLICES, 256, 0, stream>>>(src1, dst1, src2, dst2, src3, dst3, O, csr);
    k_prepw_all<<<(D_H * (128 + 320 + 320) + 255) / 256, 256, 0, stream>>>(
        W1, W2, W3, Wt1, Wt2, Wt3);

    int ggrid = (TOTN + 127) / 128;  // 469

    // layer 1: X8(fp8*inv_out,128) -> SpMM -> P8(fp8,128B) -> GEMM(K=128) -> Q8
    k_spmm_l1<<<TOTN / 4, 256, 0, stream>>>((const uint2*)X8, P8, row_ptr, csr, inv_in);
    k_gemm_mfma<0><<<ggrid, 256, 0, stream>>>(P8, 128, Wt1, b1, inv_out,
                                              Q8, nullptr, TOTN, 128);
    // layer 2
    k_spmm_big<<<TOTN / 4, 256, 0, stream>>>((const uint4*)Q8, P8, row_ptr, csr, inv_in);
    k_gemm_mfma<0><<<ggrid, 256, 0, stream>>>(P8, 320, Wt2, b2, inv_out,
                                              Q8, nullptr, TOTN, 320);
    // layer 3: GEMM fused with column max-pool (no h3 materialization)
    k_spmm_big<<<TOTN / 4, 256, 0, stream>>>((const uint4*)Q8, P8, row_ptr, csr, inv_in);
    k_gemm_mfma<1><<<ggrid, 256, 0, stream>>>(P8, 320, Wt3, b3, nullptr,
                                              nullptr, pooled, TOTN, 320);

    k_mlp<<<1, 320, 0, stream>>>(pooled, fW1, fb1, fW2, fb2, fW3, fb3, out);
}